// Round 1
// baseline (1371.500 us; speedup 1.0000x reference)
//
#include <hip/hip_runtime.h>
#include <cstdint>
#include <cstddef>

#define NN 50000
#define EE 800000
#define EP 850000   // EE + NN self-loops
#define DD 128
#define BB 1024
#define D3 384
#define NEG_SLOPE 0.2f

typedef __attribute__((ext_vector_type(8))) short short8;
typedef __attribute__((ext_vector_type(4))) float f32x4;

__device__ __forceinline__ unsigned short f2bf(float f) {
  unsigned int u = __float_as_uint(f);
  u += 0x7fffu + ((u >> 16) & 1u);
  return (unsigned short)(u >> 16);
}

// ---------------- CSR build (counting sort by dst) ----------------
__global__ void k_count(const int* __restrict__ eidx, int* __restrict__ cnt) {
  int e = blockIdx.x * 256 + threadIdx.x;
  if (e >= EP) return;
  int d = (e < EE) ? eidx[EE + e] : (e - EE);
  atomicAdd(&cnt[d], 1);
}

__global__ void k_scan1(const int* __restrict__ cnt, int* __restrict__ offs, int* __restrict__ bsum) {
  __shared__ int sd[1024];
  int tid = threadIdx.x;
  int i = blockIdx.x * 1024 + tid;
  int v = (i < NN) ? cnt[i] : 0;
  sd[tid] = v;
  __syncthreads();
  for (int off = 1; off < 1024; off <<= 1) {
    int t = (tid >= off) ? sd[tid - off] : 0;
    __syncthreads();
    sd[tid] += t;
    __syncthreads();
  }
  if (i < NN) offs[i] = sd[tid] - v;   // exclusive
  if (tid == 1023) bsum[blockIdx.x] = sd[1023];
}

__global__ void k_scan2(const int* __restrict__ bsum, int* __restrict__ bso) {
  int lane = threadIdx.x;
  int v = (lane < 49) ? bsum[lane] : 0;
  int s = v;
  #pragma unroll
  for (int off = 1; off < 64; off <<= 1) {
    int t = __shfl_up(s, off, 64);
    if (lane >= off) s += t;
  }
  if (lane < 49) bso[lane] = s - v;    // exclusive over block sums
}

__global__ void k_scan3(int* __restrict__ offs, const int* __restrict__ bso, int* __restrict__ cur) {
  int i = blockIdx.x * 256 + threadIdx.x;
  if (i >= NN) return;
  int o = offs[i] + bso[i >> 10];
  offs[i] = o;
  cur[i] = o;
}

__global__ void k_scatter(const int* __restrict__ eidx, int* __restrict__ cur, int* __restrict__ ssrc) {
  int e = blockIdx.x * 256 + threadIdx.x;
  if (e >= EP) return;
  int s, d;
  if (e < EE) { s = eidx[e]; d = eidx[EE + e]; } else { s = e - EE; d = s; }
  int p = atomicAdd(&cur[d], 1);
  ssrc[p] = s;
}

// ---------------- generic fp32 GEMM: C[M,N] = A[M,K] @ B[N,K]^T (+bias) ----------------
__global__ __launch_bounds__(256) void gemm_abt(const float* __restrict__ A, const float* __restrict__ Bm,
                                                const float* __restrict__ bias, float* __restrict__ C,
                                                int M, int Ncols, int K) {
  __shared__ float As[32][66];
  __shared__ float Bs[32][66];
  int tid = threadIdx.x;
  int tx = tid & 15, ty = tid >> 4;
  int m0 = blockIdx.x * 64, n0 = blockIdx.y * 64;
  float acc[4][4] = {};
  int lr = tid >> 2, lc = (tid & 3) * 8;
  for (int k0 = 0; k0 < K; k0 += 32) {
    float4 av0 = make_float4(0.f,0.f,0.f,0.f), av1 = av0, bv0 = av0, bv1 = av0;
    if (m0 + lr < M) {
      const float* Ap = A + (size_t)(m0 + lr) * K + k0 + lc;
      av0 = *(const float4*)Ap; av1 = *(const float4*)(Ap + 4);
    }
    if (n0 + lr < Ncols) {
      const float* Bp = Bm + (size_t)(n0 + lr) * K + k0 + lc;
      bv0 = *(const float4*)Bp; bv1 = *(const float4*)(Bp + 4);
    }
    __syncthreads();  // WAR guard vs previous tile's compute reads
    As[lc + 0][lr] = av0.x; As[lc + 1][lr] = av0.y; As[lc + 2][lr] = av0.z; As[lc + 3][lr] = av0.w;
    As[lc + 4][lr] = av1.x; As[lc + 5][lr] = av1.y; As[lc + 6][lr] = av1.z; As[lc + 7][lr] = av1.w;
    Bs[lc + 0][lr] = bv0.x; Bs[lc + 1][lr] = bv0.y; Bs[lc + 2][lr] = bv0.z; Bs[lc + 3][lr] = bv0.w;
    Bs[lc + 4][lr] = bv1.x; Bs[lc + 5][lr] = bv1.y; Bs[lc + 6][lr] = bv1.z; Bs[lc + 7][lr] = bv1.w;
    __syncthreads();
    #pragma unroll
    for (int kk = 0; kk < 32; kk++) {
      float a[4], b[4];
      #pragma unroll
      for (int i = 0; i < 4; i++) a[i] = As[kk][ty * 4 + i];
      #pragma unroll
      for (int j = 0; j < 4; j++) b[j] = Bs[kk][tx * 4 + j];
      #pragma unroll
      for (int i = 0; i < 4; i++)
        #pragma unroll
        for (int j = 0; j < 4; j++)
          acc[i][j] += a[i] * b[j];
    }
  }
  #pragma unroll
  for (int i = 0; i < 4; i++) {
    int row = m0 + ty * 4 + i;
    if (row < M) {
      #pragma unroll
      for (int j = 0; j < 4; j++) {
        int col = n0 + tx * 4 + j;
        if (col < Ncols) {
          float v = acc[i][j];
          if (bias) v += bias[col];
          C[(size_t)row * Ncols + col] = v;
        }
      }
    }
  }
}

// ---------------- attention coefficients: as_n = h@a_src, ad_n = h@a_dst ----------------
__global__ void k_attn(const float* __restrict__ h, const float* __restrict__ asrc, const float* __restrict__ adst,
                       float* __restrict__ as_, float* __restrict__ ad_) {
  int wid = (blockIdx.x * 256 + threadIdx.x) >> 6;
  int lane = threadIdx.x & 63;
  if (wid >= NN) return;
  float v0 = h[(size_t)wid * DD + lane];
  float v1 = h[(size_t)wid * DD + 64 + lane];
  float s = v0 * asrc[lane] + v1 * asrc[64 + lane];
  float d = v0 * adst[lane] + v1 * adst[64 + lane];
  #pragma unroll
  for (int o = 32; o; o >>= 1) { s += __shfl_xor(s, o, 64); d += __shfl_xor(d, o, 64); }
  if (lane == 0) { as_[wid] = s; ad_[wid] = d; }
}

// ---------------- GAT aggregation: one wave per dst node, CSR segments ----------------
__global__ void k_agg(const float* __restrict__ h, const float* __restrict__ as_, const float* __restrict__ ad_,
                      const int* __restrict__ offs, const int* __restrict__ cnt, const int* __restrict__ ssrc,
                      const float* __restrict__ bias, float* __restrict__ outp) {
  int wid = (blockIdx.x * 256 + threadIdx.x) >> 6;
  int lane = threadIdx.x & 63;
  if (wid >= NN) return;
  int start = offs[wid], deg = cnt[wid];
  float add = ad_[wid];
  float m = -3.0e38f;
  for (int i = lane; i < deg; i += 64) {
    int s = ssrc[start + i];
    float e = as_[s] + add;
    e = (e >= 0.0f) ? e : NEG_SLOPE * e;
    m = fmaxf(m, e);
  }
  #pragma unroll
  for (int o = 32; o; o >>= 1) m = fmaxf(m, __shfl_xor(m, o, 64));
  float den = 0.0f;
  for (int i = lane; i < deg; i += 64) {
    int s = ssrc[start + i];
    float e = as_[s] + add;
    e = (e >= 0.0f) ? e : NEG_SLOPE * e;
    den += __expf(e - m);
  }
  #pragma unroll
  for (int o = 32; o; o >>= 1) den += __shfl_xor(den, o, 64);
  float a0 = 0.0f, a1 = 0.0f;
  for (int i = 0; i < deg; i++) {
    int s = ssrc[start + i];              // wave-uniform broadcast load
    float e = as_[s] + add;
    e = (e >= 0.0f) ? e : NEG_SLOPE * e;
    float wg = __expf(e - m);
    a0 += wg * h[(size_t)s * DD + lane];
    a1 += wg * h[(size_t)s * DD + 64 + lane];
  }
  float inv = 1.0f / den;
  outp[(size_t)wid * DD + lane]      = a0 * inv + bias[lane];
  outp[(size_t)wid * DD + 64 + lane] = a1 * inv + bias[64 + lane];
}

// ---------------- GraphNorm ----------------
__global__ void k_gn_sum(const float* __restrict__ h, float* __restrict__ acc) {
  __shared__ float red[256];
  int tid = threadIdx.x;
  int f = tid & 127, rg = tid >> 7;
  float a = 0.0f;
  for (int r = blockIdx.x * 2 + rg; r < NN; r += gridDim.x * 2)
    a += h[(size_t)r * DD + f];
  red[tid] = a;
  __syncthreads();
  if (tid < 128) atomicAdd(&acc[f], red[tid] + red[tid + 128]);
}

__global__ void k_gn_var(const float* __restrict__ h, const float* __restrict__ muA, const float* __restrict__ ms,
                         float* __restrict__ varA) {
  __shared__ float red[256];
  int tid = threadIdx.x;
  int f = tid & 127, rg = tid >> 7;
  float sub = muA[f] * (1.0f / NN) * ms[f];
  float a = 0.0f;
  for (int r = blockIdx.x * 2 + rg; r < NN; r += gridDim.x * 2) {
    float v = h[(size_t)r * DD + f] - sub;
    a += v * v;
  }
  red[tid] = a;
  __syncthreads();
  if (tid < 128) atomicAdd(&varA[f], red[tid] + red[tid + 128]);
}

__global__ void k_gn_apply(float* __restrict__ h, const float* __restrict__ muA, const float* __restrict__ varA,
                           const float* __restrict__ ms, const float* __restrict__ w, const float* __restrict__ b) {
  const float invN = 1.0f / NN;
  for (size_t i = (size_t)blockIdx.x * 256 + threadIdx.x; i < (size_t)NN * DD; i += (size_t)gridDim.x * 256) {
    int f = (int)(i & 127);
    float v = h[i] - muA[f] * invN * ms[f];
    v = v * rsqrtf(varA[f] * invN + 1e-5f) * w[f] + b[f];
    h[i] = fmaxf(v, 0.0f);
  }
}

// ---------------- head: gather/concat ----------------
__global__ void k_gather(const float* __restrict__ h, const int* __restrict__ x, float* __restrict__ z1) {
  int i = blockIdx.x * 256 + threadIdx.x;
  if (i >= BB * D3) return;
  int b = i / D3, t = i - b * D3;
  int part = t >> 7, f = t & 127;
  int node = x[b * 3 + part];
  z1[i] = h[(size_t)node * DD + f];
}

// ---------------- BatchNorm (batch stats) + ReLU + bf16 convert ----------------
__global__ void k_bn(const float* __restrict__ z, const float* __restrict__ w, const float* __restrict__ b,
                     unsigned short* __restrict__ zb) {
  int c = blockIdx.x;
  int lane = threadIdx.x;
  float s = 0.0f, s2 = 0.0f;
  for (int r = lane; r < BB; r += 64) {
    float v = z[(size_t)r * D3 + c];
    s += v; s2 += v * v;
  }
  #pragma unroll
  for (int o = 32; o; o >>= 1) { s += __shfl_xor(s, o, 64); s2 += __shfl_xor(s2, o, 64); }
  float mu = s * (1.0f / BB);
  float var = s2 * (1.0f / BB) - mu * mu;
  float sc = rsqrtf(var + 1e-5f) * w[c];
  float sb = b[c];
  for (int r = lane; r < BB; r += 64) {
    float v = (z[(size_t)r * D3 + c] - mu) * sc + sb;
    zb[(size_t)r * D3 + c] = f2bf(fmaxf(v, 0.0f));
  }
}

// ---------------- lin2: logits[1024,50000] = zb @ lin2_W^T + b, bf16 MFMA ----------------
__global__ __launch_bounds__(256) void k_lin2(const unsigned short* __restrict__ zb,
                                              const float* __restrict__ W,
                                              const float* __restrict__ bias,
                                              float* __restrict__ out) {
  __shared__ unsigned short Ws[64 * 392];   // 64 rows x 384 k, +8 bf16 pad -> 50 KB
  int tid = threadIdx.x;
  int n0 = blockIdx.x * 64;
  for (int i = tid; i < 64 * 384; i += 256) {
    int r = i / 384, c = i - r * 384;
    float v = (n0 + r < NN) ? W[(size_t)(n0 + r) * D3 + c] : 0.0f;
    Ws[r * 392 + c] = f2bf(v);
  }
  __syncthreads();
  int wv = tid >> 6, lane = tid & 63;
  int l15 = lane & 15, q = lane >> 4;
  float bs[4];
  #pragma unroll
  for (int nt = 0; nt < 4; nt++) {
    int col = n0 + nt * 16 + l15;
    bs[nt] = (col < NN) ? bias[col] : 0.0f;
  }
  for (int it = 0; it < 4; it++) {        // 4 m-tiles of 64 rows per wave
    int mbase = (wv * 4 + it) * 64;
    f32x4 acc[4][4] = {};
    for (int ks = 0; ks < 12; ks++) {
      int k0 = ks * 32;
      short8 a[4], b[4];
      #pragma unroll
      for (int mi = 0; mi < 4; mi++)
        a[mi] = *(const short8*)(zb + (size_t)(mbase + mi * 16 + l15) * D3 + k0 + q * 8);
      #pragma unroll
      for (int nt = 0; nt < 4; nt++)
        b[nt] = *(const short8*)(&Ws[(nt * 16 + l15) * 392 + k0 + q * 8]);
      #pragma unroll
      for (int mi = 0; mi < 4; mi++)
        #pragma unroll
        for (int nt = 0; nt < 4; nt++)
          acc[mi][nt] = __builtin_amdgcn_mfma_f32_16x16x32_bf16(a[mi], b[nt], acc[mi][nt], 0, 0, 0);
    }
    #pragma unroll
    for (int mi = 0; mi < 4; mi++) {
      #pragma unroll
      for (int nt = 0; nt < 4; nt++) {
        int col = n0 + nt * 16 + l15;
        if (col < NN) {
          int rowb = mbase + mi * 16 + q * 4;
          #pragma unroll
          for (int r = 0; r < 4; r++)
            out[(size_t)(rowb + r) * NN + col] = acc[mi][nt][r] + bs[nt];
        }
      }
    }
  }
}

// ---------------- log_softmax ----------------
__global__ void k_rowred(const float* __restrict__ z, float* __restrict__ L) {
  __shared__ float red[256];
  int row = blockIdx.x, tid = threadIdx.x;
  const float* zr = z + (size_t)row * NN;
  float m = -3.0e38f;
  for (int c = tid; c < NN; c += 256) m = fmaxf(m, zr[c]);
  red[tid] = m; __syncthreads();
  for (int s = 128; s > 0; s >>= 1) { if (tid < s) red[tid] = fmaxf(red[tid], red[tid + s]); __syncthreads(); }
  float M = red[0];
  __syncthreads();
  float sum = 0.0f;
  for (int c = tid; c < NN; c += 256) sum += __expf(zr[c] - M);
  red[tid] = sum; __syncthreads();
  for (int s = 128; s > 0; s >>= 1) { if (tid < s) red[tid] += red[tid + s]; __syncthreads(); }
  if (tid == 0) L[row] = M + logf(red[0]);
}

__global__ void k_lsm(float* __restrict__ z, const float* __restrict__ L) {
  int col = blockIdx.x * 256 + threadIdx.x;
  int row = blockIdx.y;
  if (col < NN) z[(size_t)row * NN + col] -= L[row];
}

// ---------------- launcher ----------------
extern "C" void kernel_launch(void* const* d_in, const int* in_sizes, int n_in,
                              void* d_out, int out_size, void* d_ws, size_t ws_size,
                              hipStream_t stream) {
  const int*   x     = (const int*)d_in[0];
  const int*   eidx  = (const int*)d_in[1];
  const float* emb   = (const float*)d_in[2];
  const float* W1    = (const float*)d_in[3];
  const float* as1   = (const float*)d_in[4];
  const float* ad1   = (const float*)d_in[5];
  const float* b1    = (const float*)d_in[6];
  const float* gn1w  = (const float*)d_in[7];
  const float* gn1b  = (const float*)d_in[8];
  const float* gn1ms = (const float*)d_in[9];
  const float* W2    = (const float*)d_in[10];
  const float* as2   = (const float*)d_in[11];
  const float* ad2   = (const float*)d_in[12];
  const float* b2    = (const float*)d_in[13];
  const float* gn2w  = (const float*)d_in[14];
  const float* gn2b  = (const float*)d_in[15];
  const float* gn2ms = (const float*)d_in[16];
  const float* l1W   = (const float*)d_in[17];
  const float* l1b   = (const float*)d_in[18];
  const float* bnw   = (const float*)d_in[19];
  const float* bnb   = (const float*)d_in[20];
  const float* l2W   = (const float*)d_in[21];
  const float* l2b   = (const float*)d_in[22];
  float* out = (float*)d_out;

  // big N*D scratch lives in d_out (dead before k_lin2 overwrites all of d_out)
  float* h1 = out;                       // [NN, DD]
  float* h2 = out + (size_t)NN * DD;     // [NN, DD]

  char* wsb = (char*)d_ws;
  size_t o = 0;
  auto alloc = [&](size_t bytes) -> void* {
    void* p = wsb + o;
    o = (o + bytes + 255) & ~(size_t)255;
    return p;
  };
  int*   ssrc = (int*)alloc((size_t)EP * 4);
  int*   cnt  = (int*)alloc((size_t)NN * 4);
  int*   offs = (int*)alloc((size_t)NN * 4);
  int*   cur  = (int*)alloc((size_t)NN * 4);
  float* as_  = (float*)alloc((size_t)NN * 4);
  float* ad_  = (float*)alloc((size_t)NN * 4);
  int*   bsum = (int*)alloc(64 * 4);
  int*   bso  = (int*)alloc(64 * 4);
  float* muA  = (float*)alloc(DD * 4);
  float* varA = (float*)alloc(DD * 4);
  float* z1   = (float*)alloc((size_t)BB * D3 * 4);
  float* z2   = (float*)alloc((size_t)BB * D3 * 4);
  unsigned short* zbf = (unsigned short*)alloc((size_t)BB * D3 * 2);
  float* L    = (float*)alloc(BB * 4);

  // CSR by dst (built once, reused by both layers)
  hipMemsetAsync(cnt, 0, (size_t)NN * 4, stream);
  k_count  <<<(EP + 255) / 256, 256, 0, stream>>>(eidx, cnt);
  k_scan1  <<<49, 1024, 0, stream>>>(cnt, offs, bsum);
  k_scan2  <<<1, 64, 0, stream>>>(bsum, bso);
  k_scan3  <<<(NN + 255) / 256, 256, 0, stream>>>(offs, bso, cur);
  k_scatter<<<(EP + 255) / 256, 256, 0, stream>>>(eidx, cur, ssrc);

  // ---- GAT layer 1 ----
  gemm_abt<<<dim3(782, 2), 256, 0, stream>>>(emb, W1, nullptr, h1, NN, DD, DD);
  k_attn  <<<(NN + 3) / 4, 256, 0, stream>>>(h1, as1, ad1, as_, ad_);
  k_agg   <<<(NN + 3) / 4, 256, 0, stream>>>(h1, as_, ad_, offs, cnt, ssrc, b1, h2);
  hipMemsetAsync(muA, 0, DD * 4, stream);
  hipMemsetAsync(varA, 0, DD * 4, stream);
  k_gn_sum  <<<256, 256, 0, stream>>>(h2, muA);
  k_gn_var  <<<256, 256, 0, stream>>>(h2, muA, gn1ms, varA);
  k_gn_apply<<<8192, 256, 0, stream>>>(h2, muA, varA, gn1ms, gn1w, gn1b);

  // ---- GAT layer 2 ----
  gemm_abt<<<dim3(782, 2), 256, 0, stream>>>(h2, W2, nullptr, h1, NN, DD, DD);
  k_attn  <<<(NN + 3) / 4, 256, 0, stream>>>(h1, as2, ad2, as_, ad_);
  k_agg   <<<(NN + 3) / 4, 256, 0, stream>>>(h1, as_, ad_, offs, cnt, ssrc, b2, h2);
  hipMemsetAsync(muA, 0, DD * 4, stream);
  hipMemsetAsync(varA, 0, DD * 4, stream);
  k_gn_sum  <<<256, 256, 0, stream>>>(h2, muA);
  k_gn_var  <<<256, 256, 0, stream>>>(h2, muA, gn2ms, varA);
  k_gn_apply<<<8192, 256, 0, stream>>>(h2, muA, varA, gn2ms, gn2w, gn2b);

  // ---- head ----
  k_gather<<<(BB * D3 + 255) / 256, 256, 0, stream>>>(h2, x, z1);
  gemm_abt<<<dim3(16, 6), 256, 0, stream>>>(z1, l1W, l1b, z2, BB, D3, D3);
  k_bn    <<<D3, 64, 0, stream>>>(z2, bnw, bnb, zbf);
  k_lin2  <<<782, 256, 0, stream>>>(zbf, l2W, l2b, out);
  k_rowred<<<BB, 256, 0, stream>>>(out, L);
  k_lsm   <<<dim3(196, BB), 256, 0, stream>>>(out, L);
}

// Round 2
// 1203.262 us; speedup vs baseline: 1.1398x; 1.1398x over previous
//
#include <hip/hip_runtime.h>
#include <cstdint>
#include <cstddef>

#define NN 50000
#define EE 800000
#define EP 850000   // EE + NN self-loops
#define DD 128
#define BB 1024
#define D3 384
#define NEG_SLOPE 0.2f

typedef __attribute__((ext_vector_type(8))) short short8;
typedef __attribute__((ext_vector_type(4))) float f32x4;

__device__ __forceinline__ unsigned short f2bf(float f) {
  unsigned int u = __float_as_uint(f);
  u += 0x7fffu + ((u >> 16) & 1u);
  return (unsigned short)(u >> 16);
}

// ---------------- CSR build (counting sort by dst) ----------------
__global__ void k_count(const int* __restrict__ eidx, int* __restrict__ cnt) {
  int e = blockIdx.x * 256 + threadIdx.x;
  if (e >= EP) return;
  int d = (e < EE) ? eidx[EE + e] : (e - EE);
  atomicAdd(&cnt[d], 1);
}

__global__ void k_scan1(const int* __restrict__ cnt, int* __restrict__ offs, int* __restrict__ bsum) {
  __shared__ int sd[1024];
  int tid = threadIdx.x;
  int i = blockIdx.x * 1024 + tid;
  int v = (i < NN) ? cnt[i] : 0;
  sd[tid] = v;
  __syncthreads();
  for (int off = 1; off < 1024; off <<= 1) {
    int t = (tid >= off) ? sd[tid - off] : 0;
    __syncthreads();
    sd[tid] += t;
    __syncthreads();
  }
  if (i < NN) offs[i] = sd[tid] - v;   // exclusive
  if (tid == 1023) bsum[blockIdx.x] = sd[1023];
}

__global__ void k_scan2(const int* __restrict__ bsum, int* __restrict__ bso) {
  int lane = threadIdx.x;
  int v = (lane < 49) ? bsum[lane] : 0;
  int s = v;
  #pragma unroll
  for (int off = 1; off < 64; off <<= 1) {
    int t = __shfl_up(s, off, 64);
    if (lane >= off) s += t;
  }
  if (lane < 49) bso[lane] = s - v;    // exclusive over block sums
}

__global__ void k_scan3(int* __restrict__ offs, const int* __restrict__ bso, int* __restrict__ cur) {
  int i = blockIdx.x * 256 + threadIdx.x;
  if (i >= NN) return;
  int o = offs[i] + bso[i >> 10];
  offs[i] = o;
  cur[i] = o;
}

__global__ void k_scatter(const int* __restrict__ eidx, int* __restrict__ cur, int* __restrict__ ssrc) {
  int e = blockIdx.x * 256 + threadIdx.x;
  if (e >= EP) return;
  int s, d;
  if (e < EE) { s = eidx[e]; d = eidx[EE + e]; } else { s = e - EE; d = s; }
  int p = atomicAdd(&cur[d], 1);
  ssrc[p] = s;
}

// ---------------- unified MFMA GEMM: C[M,N] = A[M,K] @ B[N,K]^T (+bias) ----------------
// No LDS: A fragments from global (bf16 if ABF16, else fp32 converted inline),
// B fp32 converted inline (re-read across m-blocks is L1/L2-served).
// grid = (ceil(N/64), ceil(M/256)), block = 256 (4 waves; wave = 64 rows x 64 cols).
template<bool ABF16>
__global__ __launch_bounds__(256) void gemm_mfma(const void* __restrict__ Ap_, const float* __restrict__ Bm,
                                                 const float* __restrict__ bias, float* __restrict__ C,
                                                 int M, int Ncols, int K) {
  int tid = threadIdx.x;
  int wv = tid >> 6, lane = tid & 63;
  int l15 = lane & 15, q = lane >> 4;
  int n0 = blockIdx.x * 64;
  int mbase = blockIdx.y * 256 + wv * 64;
  int arow[4], brow[4];
  float bs[4];
  #pragma unroll
  for (int mi = 0; mi < 4; mi++) {
    int r = mbase + mi * 16 + l15;
    arow[mi] = (r < M) ? r : (M - 1);
  }
  #pragma unroll
  for (int nt = 0; nt < 4; nt++) {
    int col = n0 + nt * 16 + l15;
    brow[nt] = (col < Ncols) ? col : (Ncols - 1);
    bs[nt] = (bias != nullptr && col < Ncols) ? bias[col] : 0.0f;
  }
  f32x4 acc[4][4] = {};
  int nks = K >> 5;
  for (int ks = 0; ks < nks; ks++) {
    int k0 = ks * 32 + q * 8;
    short8 a[4], b[4];
    #pragma unroll
    for (int mi = 0; mi < 4; mi++) {
      if constexpr (ABF16) {
        a[mi] = *(const short8*)((const unsigned short*)Ap_ + (size_t)arow[mi] * K + k0);
      } else {
        const float* p = (const float*)Ap_ + (size_t)arow[mi] * K + k0;
        float4 v0 = *(const float4*)p, v1 = *(const float4*)(p + 4);
        short8 t;
        t[0] = f2bf(v0.x); t[1] = f2bf(v0.y); t[2] = f2bf(v0.z); t[3] = f2bf(v0.w);
        t[4] = f2bf(v1.x); t[5] = f2bf(v1.y); t[6] = f2bf(v1.z); t[7] = f2bf(v1.w);
        a[mi] = t;
      }
    }
    #pragma unroll
    for (int nt = 0; nt < 4; nt++) {
      const float* p = Bm + (size_t)brow[nt] * K + k0;
      float4 v0 = *(const float4*)p, v1 = *(const float4*)(p + 4);
      short8 t;
      t[0] = f2bf(v0.x); t[1] = f2bf(v0.y); t[2] = f2bf(v0.z); t[3] = f2bf(v0.w);
      t[4] = f2bf(v1.x); t[5] = f2bf(v1.y); t[6] = f2bf(v1.z); t[7] = f2bf(v1.w);
      b[nt] = t;
    }
    #pragma unroll
    for (int mi = 0; mi < 4; mi++)
      #pragma unroll
      for (int nt = 0; nt < 4; nt++)
        acc[mi][nt] = __builtin_amdgcn_mfma_f32_16x16x32_bf16(a[mi], b[nt], acc[mi][nt], 0, 0, 0);
  }
  #pragma unroll
  for (int mi = 0; mi < 4; mi++) {
    #pragma unroll
    for (int nt = 0; nt < 4; nt++) {
      int col = n0 + nt * 16 + l15;
      if (col < Ncols) {
        int rowb = mbase + mi * 16 + q * 4;
        #pragma unroll
        for (int r = 0; r < 4; r++) {
          int row = rowb + r;
          if (row < M) C[(size_t)row * Ncols + col] = acc[mi][nt][r] + bs[nt];
        }
      }
    }
  }
}

// ---------------- fp32 VALU GEMM (kept only for lin1, precision-free) ----------------
__global__ __launch_bounds__(256) void gemm_abt(const float* __restrict__ A, const float* __restrict__ Bm,
                                                const float* __restrict__ bias, float* __restrict__ C,
                                                int M, int Ncols, int K) {
  __shared__ float As[32][66];
  __shared__ float Bs[32][66];
  int tid = threadIdx.x;
  int tx = tid & 15, ty = tid >> 4;
  int m0 = blockIdx.x * 64, n0 = blockIdx.y * 64;
  float acc[4][4] = {};
  int lr = tid >> 2, lc = (tid & 3) * 8;
  for (int k0 = 0; k0 < K; k0 += 32) {
    float4 av0 = make_float4(0.f,0.f,0.f,0.f), av1 = av0, bv0 = av0, bv1 = av0;
    if (m0 + lr < M) {
      const float* Ap = A + (size_t)(m0 + lr) * K + k0 + lc;
      av0 = *(const float4*)Ap; av1 = *(const float4*)(Ap + 4);
    }
    if (n0 + lr < Ncols) {
      const float* Bp = Bm + (size_t)(n0 + lr) * K + k0 + lc;
      bv0 = *(const float4*)Bp; bv1 = *(const float4*)(Bp + 4);
    }
    __syncthreads();
    As[lc + 0][lr] = av0.x; As[lc + 1][lr] = av0.y; As[lc + 2][lr] = av0.z; As[lc + 3][lr] = av0.w;
    As[lc + 4][lr] = av1.x; As[lc + 5][lr] = av1.y; As[lc + 6][lr] = av1.z; As[lc + 7][lr] = av1.w;
    Bs[lc + 0][lr] = bv0.x; Bs[lc + 1][lr] = bv0.y; Bs[lc + 2][lr] = bv0.z; Bs[lc + 3][lr] = bv0.w;
    Bs[lc + 4][lr] = bv1.x; Bs[lc + 5][lr] = bv1.y; Bs[lc + 6][lr] = bv1.z; Bs[lc + 7][lr] = bv1.w;
    __syncthreads();
    #pragma unroll
    for (int kk = 0; kk < 32; kk++) {
      float a[4], b[4];
      #pragma unroll
      for (int i = 0; i < 4; i++) a[i] = As[kk][ty * 4 + i];
      #pragma unroll
      for (int j = 0; j < 4; j++) b[j] = Bs[kk][tx * 4 + j];
      #pragma unroll
      for (int i = 0; i < 4; i++)
        #pragma unroll
        for (int j = 0; j < 4; j++)
          acc[i][j] += a[i] * b[j];
    }
  }
  #pragma unroll
  for (int i = 0; i < 4; i++) {
    int row = m0 + ty * 4 + i;
    if (row < M) {
      #pragma unroll
      for (int j = 0; j < 4; j++) {
        int col = n0 + tx * 4 + j;
        if (col < Ncols) {
          float v = acc[i][j];
          if (bias) v += bias[col];
          C[(size_t)row * Ncols + col] = v;
        }
      }
    }
  }
}

// ---------------- attention coefficients ----------------
__global__ void k_attn(const float* __restrict__ h, const float* __restrict__ asrc, const float* __restrict__ adst,
                       float* __restrict__ as_, float* __restrict__ ad_) {
  int wid = (blockIdx.x * 256 + threadIdx.x) >> 6;
  int lane = threadIdx.x & 63;
  if (wid >= NN) return;
  float v0 = h[(size_t)wid * DD + lane];
  float v1 = h[(size_t)wid * DD + 64 + lane];
  float s = v0 * asrc[lane] + v1 * asrc[64 + lane];
  float d = v0 * adst[lane] + v1 * adst[64 + lane];
  #pragma unroll
  for (int o = 32; o; o >>= 1) { s += __shfl_xor(s, o, 64); d += __shfl_xor(d, o, 64); }
  if (lane == 0) { as_[wid] = s; ad_[wid] = d; }
}

// ---------------- GAT aggregation: one wave per dst node ----------------
__global__ void k_agg(const float* __restrict__ h, const float* __restrict__ as_, const float* __restrict__ ad_,
                      const int* __restrict__ offs, const int* __restrict__ cnt, const int* __restrict__ ssrc,
                      const float* __restrict__ bias, float* __restrict__ outp) {
  int wid = (blockIdx.x * 256 + threadIdx.x) >> 6;
  int lane = threadIdx.x & 63;
  if (wid >= NN) return;
  int start = offs[wid], deg = cnt[wid];
  float add = ad_[wid];
  float m = -3.0e38f;
  for (int i = lane; i < deg; i += 64) {
    int s = ssrc[start + i];
    float e = as_[s] + add;
    e = (e >= 0.0f) ? e : NEG_SLOPE * e;
    m = fmaxf(m, e);
  }
  #pragma unroll
  for (int o = 32; o; o >>= 1) m = fmaxf(m, __shfl_xor(m, o, 64));
  float den = 0.0f;
  for (int i = lane; i < deg; i += 64) {
    int s = ssrc[start + i];
    float e = as_[s] + add;
    e = (e >= 0.0f) ? e : NEG_SLOPE * e;
    den += __expf(e - m);
  }
  #pragma unroll
  for (int o = 32; o; o >>= 1) den += __shfl_xor(den, o, 64);
  float a0 = 0.0f, a1 = 0.0f;
  for (int i = 0; i < deg; i++) {
    int s = ssrc[start + i];              // wave-uniform broadcast load
    float e = as_[s] + add;
    e = (e >= 0.0f) ? e : NEG_SLOPE * e;
    float wg = __expf(e - m);
    a0 += wg * h[(size_t)s * DD + lane];
    a1 += wg * h[(size_t)s * DD + 64 + lane];
  }
  float inv = 1.0f / den;
  outp[(size_t)wid * DD + lane]      = a0 * inv + bias[lane];
  outp[(size_t)wid * DD + 64 + lane] = a1 * inv + bias[64 + lane];
}

// ---------------- GraphNorm: single-pass stats (E[h], E[h^2]) ----------------
__global__ void k_gn_stats(const float* __restrict__ h, float* __restrict__ acc) {
  __shared__ float r1[256], r2[256];
  int tid = threadIdx.x;
  int f = tid & 127, rg = tid >> 7;
  float a = 0.0f, b = 0.0f;
  for (int r = blockIdx.x * 2 + rg; r < NN; r += gridDim.x * 2) {
    float v = h[(size_t)r * DD + f];
    a += v; b += v * v;
  }
  r1[tid] = a; r2[tid] = b;
  __syncthreads();
  if (tid < 128) {
    atomicAdd(&acc[f], r1[tid] + r1[tid + 128]);
    atomicAdd(&acc[DD + f], r2[tid] + r2[tid + 128]);
  }
}

__global__ void k_gn_apply(float* __restrict__ h, const float* __restrict__ acc,
                           const float* __restrict__ ms, const float* __restrict__ w, const float* __restrict__ b) {
  const float invN = 1.0f / NN;
  for (size_t i = (size_t)blockIdx.x * 256 + threadIdx.x; i < (size_t)NN * DD; i += (size_t)gridDim.x * 256) {
    int f = (int)(i & 127);
    float mu = acc[f] * invN;
    float qm = acc[DD + f] * invN;
    float sub = mu * ms[f];
    float var = qm - 2.0f * sub * mu + sub * sub;  // mean((h - mu*ms)^2)
    float v = (h[i] - sub) * rsqrtf(var + 1e-5f) * w[f] + b[f];
    h[i] = fmaxf(v, 0.0f);
  }
}

// ---------------- head: gather/concat ----------------
__global__ void k_gather(const float* __restrict__ h, const int* __restrict__ x, float* __restrict__ z1) {
  int i = blockIdx.x * 256 + threadIdx.x;
  if (i >= BB * D3) return;
  int b = i / D3, t = i - b * D3;
  int part = t >> 7, f = t & 127;
  int node = x[b * 3 + part];
  z1[i] = h[(size_t)node * DD + f];
}

// ---------------- BatchNorm (batch stats) + ReLU + bf16 convert ----------------
__global__ void k_bn(const float* __restrict__ z, const float* __restrict__ w, const float* __restrict__ b,
                     unsigned short* __restrict__ zb) {
  int c = blockIdx.x;
  int lane = threadIdx.x;
  float s = 0.0f, s2 = 0.0f;
  for (int r = lane; r < BB; r += 64) {
    float v = z[(size_t)r * D3 + c];
    s += v; s2 += v * v;
  }
  #pragma unroll
  for (int o = 32; o; o >>= 1) { s += __shfl_xor(s, o, 64); s2 += __shfl_xor(s2, o, 64); }
  float mu = s * (1.0f / BB);
  float var = s2 * (1.0f / BB) - mu * mu;
  float sc = rsqrtf(var + 1e-5f) * w[c];
  float sb = b[c];
  for (int r = lane; r < BB; r += 64) {
    float v = (z[(size_t)r * D3 + c] - mu) * sc + sb;
    zb[(size_t)r * D3 + c] = f2bf(fmaxf(v, 0.0f));
  }
}

// ---------------- fused log_softmax: one block per row ----------------
// Pass 1: online max+sumexp (one HBM read). Pass 2: subtract (row is L3-resident).
__global__ __launch_bounds__(256) void k_softmax(float* __restrict__ z) {
  __shared__ float sm[256], ss[256];
  int row = blockIdx.x, tid = threadIdx.x;
  float* zr = z + (size_t)row * NN;
  float m = -3.0e38f, s = 0.0f;
  for (int c = tid; c < NN; c += 256) {
    float v = zr[c];
    if (v > m) { s *= __expf(m - v); m = v; }
    s += __expf(v - m);
  }
  sm[tid] = m; ss[tid] = s;
  __syncthreads();
  for (int st = 128; st > 0; st >>= 1) {
    if (tid < st) {
      float m2 = sm[tid + st], s2 = ss[tid + st];
      float M = fmaxf(sm[tid], m2);
      ss[tid] = ss[tid] * __expf(sm[tid] - M) + s2 * __expf(m2 - M);
      sm[tid] = M;
    }
    __syncthreads();
  }
  float L = sm[0] + logf(ss[0]);
  for (int c = tid; c < NN; c += 256) zr[c] -= L;
}

// ---------------- launcher ----------------
extern "C" void kernel_launch(void* const* d_in, const int* in_sizes, int n_in,
                              void* d_out, int out_size, void* d_ws, size_t ws_size,
                              hipStream_t stream) {
  const int*   x     = (const int*)d_in[0];
  const int*   eidx  = (const int*)d_in[1];
  const float* emb   = (const float*)d_in[2];
  const float* W1    = (const float*)d_in[3];
  const float* as1   = (const float*)d_in[4];
  const float* ad1   = (const float*)d_in[5];
  const float* b1    = (const float*)d_in[6];
  const float* gn1w  = (const float*)d_in[7];
  const float* gn1b  = (const float*)d_in[8];
  const float* gn1ms = (const float*)d_in[9];
  const float* W2    = (const float*)d_in[10];
  const float* as2   = (const float*)d_in[11];
  const float* ad2   = (const float*)d_in[12];
  const float* b2    = (const float*)d_in[13];
  const float* gn2w  = (const float*)d_in[14];
  const float* gn2b  = (const float*)d_in[15];
  const float* gn2ms = (const float*)d_in[16];
  const float* l1W   = (const float*)d_in[17];
  const float* l1b   = (const float*)d_in[18];
  const float* bnw   = (const float*)d_in[19];
  const float* bnb   = (const float*)d_in[20];
  const float* l2W   = (const float*)d_in[21];
  const float* l2b   = (const float*)d_in[22];
  float* out = (float*)d_out;

  // big N*D scratch lives in d_out (dead before the final lin2 overwrites d_out)
  float* h1 = out;                       // [NN, DD]
  float* h2 = out + (size_t)NN * DD;     // [NN, DD]

  char* wsb = (char*)d_ws;
  size_t o = 0;
  auto alloc = [&](size_t bytes) -> void* {
    void* p = wsb + o;
    o = (o + bytes + 255) & ~(size_t)255;
    return p;
  };
  int*   ssrc = (int*)alloc((size_t)EP * 4);
  int*   cnt  = (int*)alloc((size_t)NN * 4);
  int*   offs = (int*)alloc((size_t)NN * 4);
  int*   cur  = (int*)alloc((size_t)NN * 4);
  float* as_  = (float*)alloc((size_t)NN * 4);
  float* ad_  = (float*)alloc((size_t)NN * 4);
  int*   bsum = (int*)alloc(64 * 4);
  int*   bso  = (int*)alloc(64 * 4);
  float* gnacc= (float*)alloc(2 * DD * 4);
  float* z1   = (float*)alloc((size_t)BB * D3 * 4);
  float* z2   = (float*)alloc((size_t)BB * D3 * 4);
  unsigned short* zbf = (unsigned short*)alloc((size_t)BB * D3 * 2);

  // CSR by dst (built once, reused by both layers)
  hipMemsetAsync(cnt, 0, (size_t)NN * 4, stream);
  k_count  <<<(EP + 255) / 256, 256, 0, stream>>>(eidx, cnt);
  k_scan1  <<<49, 1024, 0, stream>>>(cnt, offs, bsum);
  k_scan2  <<<1, 64, 0, stream>>>(bsum, bso);
  k_scan3  <<<(NN + 255) / 256, 256, 0, stream>>>(offs, bso, cur);
  k_scatter<<<(EP + 255) / 256, 256, 0, stream>>>(eidx, cur, ssrc);

  // ---- GAT layer 1 ----
  gemm_mfma<false><<<dim3(2, 196), 256, 0, stream>>>(emb, W1, nullptr, h1, NN, DD, DD);
  k_attn  <<<(NN + 3) / 4, 256, 0, stream>>>(h1, as1, ad1, as_, ad_);
  k_agg   <<<(NN + 3) / 4, 256, 0, stream>>>(h1, as_, ad_, offs, cnt, ssrc, b1, h2);
  hipMemsetAsync(gnacc, 0, 2 * DD * 4, stream);
  k_gn_stats<<<256, 256, 0, stream>>>(h2, gnacc);
  k_gn_apply<<<8192, 256, 0, stream>>>(h2, gnacc, gn1ms, gn1w, gn1b);

  // ---- GAT layer 2 ----
  gemm_mfma<false><<<dim3(2, 196), 256, 0, stream>>>(h2, W2, nullptr, h1, NN, DD, DD);
  k_attn  <<<(NN + 3) / 4, 256, 0, stream>>>(h1, as2, ad2, as_, ad_);
  k_agg   <<<(NN + 3) / 4, 256, 0, stream>>>(h1, as_, ad_, offs, cnt, ssrc, b2, h2);
  hipMemsetAsync(gnacc, 0, 2 * DD * 4, stream);
  k_gn_stats<<<256, 256, 0, stream>>>(h2, gnacc);
  k_gn_apply<<<8192, 256, 0, stream>>>(h2, gnacc, gn2ms, gn2w, gn2b);

  // ---- head ----
  k_gather<<<(BB * D3 + 255) / 256, 256, 0, stream>>>(h2, x, z1);
  gemm_abt<<<dim3(16, 6), 256, 0, stream>>>(z1, l1W, l1b, z2, BB, D3, D3);
  k_bn    <<<D3, 64, 0, stream>>>(z2, bnw, bnb, zbf);
  gemm_mfma<true><<<dim3(782, 4), 256, 0, stream>>>(zbf, l2W, l2b, out, BB, NN, D3);
  k_softmax<<<BB, 256, 0, stream>>>(out);
}

// Round 3
// 1014.048 us; speedup vs baseline: 1.3525x; 1.1866x over previous
//
#include <hip/hip_runtime.h>
#include <cstdint>
#include <cstddef>

#define NN 50000
#define EE 800000
#define EP 850000   // EE + NN self-loops
#define DD 128
#define BB 1024
#define D3 384
#define NEG_SLOPE 0.2f

typedef __attribute__((ext_vector_type(8))) short short8;
typedef __attribute__((ext_vector_type(4))) float f32x4;
typedef unsigned short u16;
typedef unsigned int u32;

__device__ __forceinline__ u16 f2bf(float f) {
  u32 u = __float_as_uint(f);
  u += 0x7fffu + ((u >> 16) & 1u);
  return (u16)(u >> 16);
}
__device__ __forceinline__ float bflo(u32 u) { return __uint_as_float(u << 16); }
__device__ __forceinline__ float bfhi(u32 u) { return __uint_as_float(u & 0xffff0000u); }

// async global->LDS 16B: per-lane global addr, wave-uniform LDS base (+lane*16 by HW)
__device__ __forceinline__ void gl2lds16(const u16* g, u16* lds_base_uniform) {
  __builtin_amdgcn_global_load_lds((const __attribute__((address_space(1))) u32*)g,
                                   (__attribute__((address_space(3))) u32*)lds_base_uniform,
                                   16, 0, 0);
}

// ---------------- fp32 -> bf16 bulk convert (n multiple of 4) ----------------
__global__ void k_f2bf(const float* __restrict__ s, u16* __restrict__ d, int n4) {
  int i = blockIdx.x * 256 + threadIdx.x;
  if (i >= n4) return;
  float4 v = ((const float4*)s)[i];
  ushort4 o;
  o.x = f2bf(v.x); o.y = f2bf(v.y); o.z = f2bf(v.z); o.w = f2bf(v.w);
  ((ushort4*)d)[i] = o;
}

// ---------------- CSR build (counting sort by dst) ----------------
__global__ void k_count(const int* __restrict__ eidx, int* __restrict__ cnt) {
  int e = blockIdx.x * 256 + threadIdx.x;
  if (e >= EP) return;
  int d = (e < EE) ? eidx[EE + e] : (e - EE);
  atomicAdd(&cnt[d], 1);
}

__global__ void k_scan1(const int* __restrict__ cnt, int* __restrict__ offs, int* __restrict__ bsum) {
  __shared__ int sd[1024];
  int tid = threadIdx.x;
  int i = blockIdx.x * 1024 + tid;
  int v = (i < NN) ? cnt[i] : 0;
  sd[tid] = v;
  __syncthreads();
  for (int off = 1; off < 1024; off <<= 1) {
    int t = (tid >= off) ? sd[tid - off] : 0;
    __syncthreads();
    sd[tid] += t;
    __syncthreads();
  }
  if (i < NN) offs[i] = sd[tid] - v;   // exclusive
  if (tid == 1023) bsum[blockIdx.x] = sd[1023];
}

__global__ void k_scan2(const int* __restrict__ bsum, int* __restrict__ bso) {
  int lane = threadIdx.x;
  int v = (lane < 49) ? bsum[lane] : 0;
  int s = v;
  #pragma unroll
  for (int off = 1; off < 64; off <<= 1) {
    int t = __shfl_up(s, off, 64);
    if (lane >= off) s += t;
  }
  if (lane < 49) bso[lane] = s - v;
}

__global__ void k_scan3(int* __restrict__ offs, const int* __restrict__ bso, int* __restrict__ cur) {
  int i = blockIdx.x * 256 + threadIdx.x;
  if (i >= NN) return;
  int o = offs[i] + bso[i >> 10];
  offs[i] = o;
  cur[i] = o;
}

__global__ void k_scatter(const int* __restrict__ eidx, int* __restrict__ cur, int* __restrict__ ssrc) {
  int e = blockIdx.x * 256 + threadIdx.x;
  if (e >= EP) return;
  int s, d;
  if (e < EE) { s = eidx[e]; d = eidx[EE + e]; } else { s = e - EE; d = s; }
  int p = atomicAdd(&cur[d], 1);
  ssrc[p] = s;
}

// ---------------- m97-style tiled MFMA GEMM ----------------
// C[M,N] = A[M,K] @ B[N,K]^T (+bias). A bf16. B bf16 (gl2lds) or fp32 (load-convert-ds_write).
// 128x128 tile, BK=64, XOR-swizzled LDS (chunk c' = c ^ (row&7)) -> conflict-free ds_read_b128.
// block = 256 thr / 4 waves; wave computes 64x64 (mh = w&1, nh = w>>1).
template<bool B_IS_F32, bool OUT_BF16>
__global__ __launch_bounds__(256) void gemm_tile(const u16* __restrict__ A, const void* __restrict__ Bv,
                                                 const float* __restrict__ bias, void* __restrict__ Cv,
                                                 int M, int N, int K) {
  __shared__ u16 As[16 * 512];   // 16 KB: [128 rows][64 k] bf16, swizzled
  __shared__ u16 Bs[16 * 512];
  int tid = threadIdx.x;
  int w = tid >> 6, lane = tid & 63;
  int l15 = lane & 15, q = lane >> 4;
  int n0 = blockIdx.x * 128, m0 = blockIdx.y * 128;
  int mh = w & 1, nh = w >> 1;

  // staging lane geometry (A, and B when bf16)
  int lr = lane >> 3;                 // row-in-8
  int cg = (lane & 7) ^ lr;           // global chunk to fetch for this lane's slot

  f32x4 acc[4][4] = {};

  for (int kt = 0; kt < K; kt += 64) {
    // ---- stage A (4 insts/thread wave-uniform LDS base) ----
    #pragma unroll
    for (int i = 0; i < 4; i++) {
      int inst = (w << 2) | i;
      int row = inst * 8 + lr;
      int grow = m0 + row; if (grow > M - 1) grow = M - 1;
      gl2lds16(A + (size_t)grow * K + kt + cg * 8, &As[inst * 512]);
    }
    // ---- stage B ----
    if constexpr (!B_IS_F32) {
      const u16* Bb = (const u16*)Bv;
      #pragma unroll
      for (int i = 0; i < 4; i++) {
        int inst = (w << 2) | i;
        int row = inst * 8 + lr;
        int gn = n0 + row; if (gn > N - 1) gn = N - 1;
        gl2lds16(Bb + (size_t)gn * K + kt + cg * 8, &Bs[inst * 512]);
      }
    } else {
      const float* Bf = (const float*)Bv;
      int row = tid >> 1, half = tid & 1;
      int gn = n0 + row; if (gn > N - 1) gn = N - 1;
      const float* gp = Bf + (size_t)gn * K + kt;
      #pragma unroll
      for (int j = 0; j < 4; j++) {
        int c = half * 4 + j;
        float4 v0 = *(const float4*)(gp + c * 8);
        float4 v1 = *(const float4*)(gp + c * 8 + 4);
        short8 t;
        t[0] = f2bf(v0.x); t[1] = f2bf(v0.y); t[2] = f2bf(v0.z); t[3] = f2bf(v0.w);
        t[4] = f2bf(v1.x); t[5] = f2bf(v1.y); t[6] = f2bf(v1.z); t[7] = f2bf(v1.w);
        int c2 = c ^ (row & 7);
        *(short8*)(&Bs[row * 64 + c2 * 8]) = t;
      }
    }
    __builtin_amdgcn_s_waitcnt(0x0f70);  // vmcnt(0) for global_load_lds
    __syncthreads();

    // ---- compute: 2 kk-steps x 16 MFMA ----
    #pragma unroll
    for (int kk = 0; kk < 2; kk++) {
      short8 a[4], b[4];
      int cbase = kk * 4 + q;
      int csw = cbase ^ (l15 & 7);
      #pragma unroll
      for (int mi = 0; mi < 4; mi++) {
        int row = (mh * 4 + mi) * 16 + l15;
        a[mi] = *(const short8*)(&As[row * 64 + csw * 8]);
      }
      #pragma unroll
      for (int nt = 0; nt < 4; nt++) {
        int row = (nh * 4 + nt) * 16 + l15;
        b[nt] = *(const short8*)(&Bs[row * 64 + csw * 8]);
      }
      #pragma unroll
      for (int mi = 0; mi < 4; mi++)
        #pragma unroll
        for (int nt = 0; nt < 4; nt++)
          acc[mi][nt] = __builtin_amdgcn_mfma_f32_16x16x32_bf16(a[mi], b[nt], acc[mi][nt], 0, 0, 0);
    }
    __syncthreads();   // WAR before next stage
  }

  // ---- epilogue ----
  float bsv[4];
  #pragma unroll
  for (int nt = 0; nt < 4; nt++) {
    int col = n0 + nh * 64 + nt * 16 + l15;
    bsv[nt] = (bias != nullptr && col < N) ? bias[col] : 0.0f;
  }
  #pragma unroll
  for (int mi = 0; mi < 4; mi++) {
    int rowg = m0 + mh * 64 + mi * 16 + q * 4;
    #pragma unroll
    for (int nt = 0; nt < 4; nt++) {
      int col = n0 + nh * 64 + nt * 16 + l15;
      if (col < N) {
        #pragma unroll
        for (int r = 0; r < 4; r++) {
          int rw = rowg + r;
          if (rw < M) {
            float v = acc[mi][nt][r] + bsv[nt];
            if constexpr (OUT_BF16) ((u16*)Cv)[(size_t)rw * N + col] = f2bf(v);
            else                    ((float*)Cv)[(size_t)rw * N + col] = v;
          }
        }
      }
    }
  }
}

// ---------------- attention coefficients (bf16 h) ----------------
__global__ void k_attn(const u16* __restrict__ hb, const float* __restrict__ asrc, const float* __restrict__ adst,
                       float* __restrict__ as_, float* __restrict__ ad_) {
  int wid = (blockIdx.x * 256 + threadIdx.x) >> 6;
  int lane = threadIdx.x & 63;
  if (wid >= NN) return;
  u32 u = ((const u32*)(hb + (size_t)wid * DD))[lane];
  float v0 = bflo(u), v1 = bfhi(u);
  float s = v0 * asrc[2 * lane] + v1 * asrc[2 * lane + 1];
  float d = v0 * adst[2 * lane] + v1 * adst[2 * lane + 1];
  #pragma unroll
  for (int o = 32; o; o >>= 1) { s += __shfl_xor(s, o, 64); d += __shfl_xor(d, o, 64); }
  if (lane == 0) { as_[wid] = s; ad_[wid] = d; }
}

// ---------------- GAT aggregation: one wave per dst node (bf16 h) ----------------
__global__ void k_agg(const u16* __restrict__ hb, const float* __restrict__ as_, const float* __restrict__ ad_,
                      const int* __restrict__ offs, const int* __restrict__ cnt, const int* __restrict__ ssrc,
                      const float* __restrict__ bias, float* __restrict__ outp) {
  int wid = (blockIdx.x * 256 + threadIdx.x) >> 6;
  int lane = threadIdx.x & 63;
  if (wid >= NN) return;
  int start = offs[wid], deg = cnt[wid];
  float add = ad_[wid];
  float m = -3.0e38f;
  for (int i = lane; i < deg; i += 64) {
    int s = ssrc[start + i];
    float e = as_[s] + add;
    e = (e >= 0.0f) ? e : NEG_SLOPE * e;
    m = fmaxf(m, e);
  }
  #pragma unroll
  for (int o = 32; o; o >>= 1) m = fmaxf(m, __shfl_xor(m, o, 64));
  float den = 0.0f;
  for (int i = lane; i < deg; i += 64) {
    int s = ssrc[start + i];
    float e = as_[s] + add;
    e = (e >= 0.0f) ? e : NEG_SLOPE * e;
    den += __expf(e - m);
  }
  #pragma unroll
  for (int o = 32; o; o >>= 1) den += __shfl_xor(den, o, 64);

  const u32* hp = (const u32*)hb;   // row stride 64 u32
  float a0 = 0.0f, a1 = 0.0f;
  int i = 0;
  for (; i + 4 <= deg; i += 4) {
    int s0 = ssrc[start + i + 0], s1 = ssrc[start + i + 1];
    int s2 = ssrc[start + i + 2], s3 = ssrc[start + i + 3];
    u32 u0 = hp[(size_t)s0 * 64 + lane];
    u32 u1 = hp[(size_t)s1 * 64 + lane];
    u32 u2 = hp[(size_t)s2 * 64 + lane];
    u32 u3 = hp[(size_t)s3 * 64 + lane];
    float e0 = as_[s0] + add, e1 = as_[s1] + add, e2 = as_[s2] + add, e3 = as_[s3] + add;
    e0 = (e0 >= 0.0f) ? e0 : NEG_SLOPE * e0;
    e1 = (e1 >= 0.0f) ? e1 : NEG_SLOPE * e1;
    e2 = (e2 >= 0.0f) ? e2 : NEG_SLOPE * e2;
    e3 = (e3 >= 0.0f) ? e3 : NEG_SLOPE * e3;
    float w0 = __expf(e0 - m), w1 = __expf(e1 - m), w2 = __expf(e2 - m), w3 = __expf(e3 - m);
    a0 += w0 * bflo(u0) + w1 * bflo(u1) + w2 * bflo(u2) + w3 * bflo(u3);
    a1 += w0 * bfhi(u0) + w1 * bfhi(u1) + w2 * bfhi(u2) + w3 * bfhi(u3);
  }
  for (; i < deg; i++) {
    int s = ssrc[start + i];
    u32 u = hp[(size_t)s * 64 + lane];
    float e = as_[s] + add;
    e = (e >= 0.0f) ? e : NEG_SLOPE * e;
    float wg = __expf(e - m);
    a0 += wg * bflo(u);
    a1 += wg * bfhi(u);
  }
  float inv = 1.0f / den;
  float2 st;
  st.x = a0 * inv + bias[2 * lane];
  st.y = a1 * inv + bias[2 * lane + 1];
  *(float2*)(outp + (size_t)wid * DD + 2 * lane) = st;
}

// ---------------- GraphNorm: single-pass stats (E[h], E[h^2]) ----------------
__global__ void k_gn_stats(const float* __restrict__ h, float* __restrict__ acc) {
  __shared__ float r1[256], r2[256];
  int tid = threadIdx.x;
  int f = tid & 127, rg = tid >> 7;
  float a = 0.0f, b = 0.0f;
  for (int r = blockIdx.x * 2 + rg; r < NN; r += gridDim.x * 2) {
    float v = h[(size_t)r * DD + f];
    a += v; b += v * v;
  }
  r1[tid] = a; r2[tid] = b;
  __syncthreads();
  if (tid < 128) {
    atomicAdd(&acc[f], r1[tid] + r1[tid + 128]);
    atomicAdd(&acc[DD + f], r2[tid] + r2[tid + 128]);
  }
}

// apply + ReLU in place; optionally emit bf16 copy for next GEMM's A
__global__ void k_gn_apply(float* __restrict__ h, const float* __restrict__ acc,
                           const float* __restrict__ ms, const float* __restrict__ w, const float* __restrict__ b,
                           u16* __restrict__ hb) {
  const float invN = 1.0f / NN;
  for (size_t i = (size_t)blockIdx.x * 256 + threadIdx.x; i < (size_t)NN * DD; i += (size_t)gridDim.x * 256) {
    int f = (int)(i & 127);
    float mu = acc[f] * invN;
    float qm = acc[DD + f] * invN;
    float sub = mu * ms[f];
    float var = qm - 2.0f * sub * mu + sub * sub;
    float v = (h[i] - sub) * rsqrtf(var + 1e-5f) * w[f] + b[f];
    v = fmaxf(v, 0.0f);
    h[i] = v;
    if (hb) hb[i] = f2bf(v);
  }
}

// ---------------- head: gather/concat -> bf16 ----------------
__global__ void k_gather(const float* __restrict__ h, const int* __restrict__ x, u16* __restrict__ z1b) {
  int i = blockIdx.x * 256 + threadIdx.x;
  if (i >= BB * D3) return;
  int b = i / D3, t = i - b * D3;
  int part = t >> 7, f = t & 127;
  int node = x[b * 3 + part];
  z1b[i] = f2bf(h[(size_t)node * DD + f]);
}

// ---------------- BatchNorm (batch stats) + ReLU + bf16 ----------------
__global__ void k_bn(const float* __restrict__ z, const float* __restrict__ w, const float* __restrict__ b,
                     u16* __restrict__ zb) {
  int c = blockIdx.x;
  int lane = threadIdx.x;
  float s = 0.0f, s2 = 0.0f;
  for (int r = lane; r < BB; r += 64) {
    float v = z[(size_t)r * D3 + c];
    s += v; s2 += v * v;
  }
  #pragma unroll
  for (int o = 32; o; o >>= 1) { s += __shfl_xor(s, o, 64); s2 += __shfl_xor(s2, o, 64); }
  float mu = s * (1.0f / BB);
  float var = s2 * (1.0f / BB) - mu * mu;
  float sc = rsqrtf(var + 1e-5f) * w[c];
  float sb = b[c];
  for (int r = lane; r < BB; r += 64) {
    float v = (z[(size_t)r * D3 + c] - mu) * sc + sb;
    zb[(size_t)r * D3 + c] = f2bf(fmaxf(v, 0.0f));
  }
}

// ---------------- fused log_softmax: one block per row ----------------
__global__ __launch_bounds__(256) void k_softmax(float* __restrict__ z) {
  __shared__ float sm[256], ss[256];
  int row = blockIdx.x, tid = threadIdx.x;
  float* zr = z + (size_t)row * NN;
  float m = -3.0e38f, s = 0.0f;
  for (int c = tid; c < NN; c += 256) {
    float v = zr[c];
    if (v > m) { s *= __expf(m - v); m = v; }
    s += __expf(v - m);
  }
  sm[tid] = m; ss[tid] = s;
  __syncthreads();
  for (int st = 128; st > 0; st >>= 1) {
    if (tid < st) {
      float m2 = sm[tid + st], s2 = ss[tid + st];
      float M = fmaxf(sm[tid], m2);
      ss[tid] = ss[tid] * __expf(sm[tid] - M) + s2 * __expf(m2 - M);
      sm[tid] = M;
    }
    __syncthreads();
  }
  float L = sm[0] + logf(ss[0]);
  for (int c = tid; c < NN; c += 256) zr[c] -= L;
}

// ---------------- launcher ----------------
extern "C" void kernel_launch(void* const* d_in, const int* in_sizes, int n_in,
                              void* d_out, int out_size, void* d_ws, size_t ws_size,
                              hipStream_t stream) {
  const int*   x     = (const int*)d_in[0];
  const int*   eidx  = (const int*)d_in[1];
  const float* emb   = (const float*)d_in[2];
  const float* W1    = (const float*)d_in[3];
  const float* as1   = (const float*)d_in[4];
  const float* ad1   = (const float*)d_in[5];
  const float* b1    = (const float*)d_in[6];
  const float* gn1w  = (const float*)d_in[7];
  const float* gn1b  = (const float*)d_in[8];
  const float* gn1ms = (const float*)d_in[9];
  const float* W2    = (const float*)d_in[10];
  const float* as2   = (const float*)d_in[11];
  const float* ad2   = (const float*)d_in[12];
  const float* b2    = (const float*)d_in[13];
  const float* gn2w  = (const float*)d_in[14];
  const float* gn2b  = (const float*)d_in[15];
  const float* gn2ms = (const float*)d_in[16];
  const float* l1W   = (const float*)d_in[17];
  const float* l1b   = (const float*)d_in[18];
  const float* bnw   = (const float*)d_in[19];
  const float* bnb   = (const float*)d_in[20];
  const float* l2W   = (const float*)d_in[21];
  const float* l2b   = (const float*)d_in[22];
  float* out = (float*)d_out;
  char*  dob = (char*)d_out;

  // big intermediates live in d_out (all dead before lin2 overwrites d_out)
  u16*   embb = (u16*)(dob);                    // 12.8 MB, dead after L1 gemm
  u16*   h1b  = (u16*)(dob + (16u << 20));      // 12.8 MB, dead after L2 agg
  float* h2   = (float*)(dob + (32u << 20));    // 25.6 MB, dead after gather
  u16*   h2b  = (u16*)(dob + (64u << 20));      // 12.8 MB, dead after L2 gemm

  char* wsb = (char*)d_ws;
  size_t o = 0;
  auto alloc = [&](size_t bytes) -> void* {
    void* p = wsb + o;
    o = (o + bytes + 255) & ~(size_t)255;
    return p;
  };
  int*   ssrc = (int*)alloc((size_t)EP * 4);
  int*   cnt  = (int*)alloc((size_t)NN * 4);
  int*   offs = (int*)alloc((size_t)NN * 4);
  int*   cur  = (int*)alloc((size_t)NN * 4);
  float* as_  = (float*)alloc((size_t)NN * 4);
  float* ad_  = (float*)alloc((size_t)NN * 4);
  int*   bsum = (int*)alloc(64 * 4);
  int*   bso  = (int*)alloc(64 * 4);
  float* gnacc= (float*)alloc(2 * DD * 4);
  u16*   W1b  = (u16*)alloc((size_t)DD * DD * 2);
  u16*   W2b  = (u16*)alloc((size_t)DD * DD * 2);
  u16*   l1Wb = (u16*)alloc((size_t)D3 * D3 * 2);
  u16*   z1b  = (u16*)alloc((size_t)BB * D3 * 2);
  float* z2   = (float*)alloc((size_t)BB * D3 * 4);
  u16*   zbf  = (u16*)alloc((size_t)BB * D3 * 2);

  // ---- weight/embedding converts ----
  k_f2bf<<<(NN * DD / 4 + 255) / 256, 256, 0, stream>>>(emb, embb, NN * DD / 4);
  k_f2bf<<<(DD * DD / 4 + 255) / 256, 256, 0, stream>>>(W1, W1b, DD * DD / 4);
  k_f2bf<<<(DD * DD / 4 + 255) / 256, 256, 0, stream>>>(W2, W2b, DD * DD / 4);
  k_f2bf<<<(D3 * D3 / 4 + 255) / 256, 256, 0, stream>>>(l1W, l1Wb, D3 * D3 / 4);

  // ---- CSR by dst ----
  hipMemsetAsync(cnt, 0, (size_t)NN * 4, stream);
  k_count  <<<(EP + 255) / 256, 256, 0, stream>>>(eidx, cnt);
  k_scan1  <<<49, 1024, 0, stream>>>(cnt, offs, bsum);
  k_scan2  <<<1, 64, 0, stream>>>(bsum, bso);
  k_scan3  <<<(NN + 255) / 256, 256, 0, stream>>>(offs, bso, cur);
  k_scatter<<<(EP + 255) / 256, 256, 0, stream>>>(eidx, cur, ssrc);

  // ---- GAT layer 1 ----
  gemm_tile<false, true><<<dim3(1, 391), 256, 0, stream>>>(embb, W1b, nullptr, h1b, NN, DD, DD);
  k_attn<<<(NN + 3) / 4, 256, 0, stream>>>(h1b, as1, ad1, as_, ad_);
  k_agg <<<(NN + 3) / 4, 256, 0, stream>>>(h1b, as_, ad_, offs, cnt, ssrc, b1, h2);
  hipMemsetAsync(gnacc, 0, 2 * DD * 4, stream);
  k_gn_stats<<<256, 256, 0, stream>>>(h2, gnacc);
  k_gn_apply<<<8192, 256, 0, stream>>>(h2, gnacc, gn1ms, gn1w, gn1b, h2b);

  // ---- GAT layer 2 ----
  gemm_tile<false, true><<<dim3(1, 391), 256, 0, stream>>>(h2b, W2b, nullptr, h1b, NN, DD, DD);
  k_attn<<<(NN + 3) / 4, 256, 0, stream>>>(h1b, as2, ad2, as_, ad_);
  k_agg <<<(NN + 3) / 4, 256, 0, stream>>>(h1b, as_, ad_, offs, cnt, ssrc, b2, h2);
  hipMemsetAsync(gnacc, 0, 2 * DD * 4, stream);
  k_gn_stats<<<256, 256, 0, stream>>>(h2, gnacc);
  k_gn_apply<<<8192, 256, 0, stream>>>(h2, gnacc, gn2ms, gn2w, gn2b, nullptr);

  // ---- head ----
  k_gather<<<(BB * D3 + 255) / 256, 256, 0, stream>>>(h2, x, z1b);
  gemm_tile<false, false><<<dim3(3, 8), 256, 0, stream>>>(z1b, l1Wb, l1b, z2, BB, D3, D3);
  k_bn<<<D3, 64, 0, stream>>>(z2, bnw, bnb, zbf);
  gemm_tile<true, false><<<dim3(391, 8), 256, 0, stream>>>(zbf, l2W, l2b, out, BB, NN, D3);
  k_softmax<<<BB, 256, 0, stream>>>(out);
}